// Round 2
// baseline (8211.592 us; speedup 1.0000x reference)
//
#include <hip/hip_runtime.h>
#include <stdint.h>

// ---------------- problem constants ----------------
#define H      2048
#define SEQ    1024
#define NB     256      // persistent blocks (1 per CU)
#define NT     512      // threads per block (8 waves)
#define JPB    8        // hidden units per block per layer (H / NB)
#define ROUNDS (SEQ + 1)

typedef _Float16 f16;
typedef _Float16 f16x2 __attribute__((ext_vector_type(2)));
typedef unsigned int u32;
typedef unsigned long long u64;

// ---------------- workspace layout (bytes) ----------------
// tags: int[NB] @ 0
// h0buf: f16[SEQ+2][H] @ H0_OFF   (h0buf[t] = layer-0 hidden after t steps)
// h1buf: f16[SEQ+2][H] @ H1_OFF
static const size_t TAG_OFF = 0;
static const size_t H0_OFF  = 4096;
static const size_t HBYTES  = (size_t)(SEQ + 2) * H * 2;   // 4,202,496
static const size_t H1_OFF  = H0_OFF + HBYTES;
static const size_t WS_NEED = H1_OFF + HBYTES;             // ~8.4 MB

// ---------------- helpers ----------------
__device__ __forceinline__ u32 pk2(float a, float b) {
  f16x2 h;
  h.x = (f16)a;  // RNE
  h.y = (f16)b;
  return __builtin_bit_cast(u32, h);
}

__device__ __forceinline__ float dot2(u32 a, u32 b, float c) {
#if __has_builtin(__builtin_amdgcn_fdot2)
  return __builtin_amdgcn_fdot2(__builtin_bit_cast(f16x2, a),
                                __builtin_bit_cast(f16x2, b), c, false);
#else
  f16x2 av = __builtin_bit_cast(f16x2, a);
  f16x2 bv = __builtin_bit_cast(f16x2, b);
  return c + (float)av.x * (float)bv.x + (float)av.y * (float)bv.y;
#endif
}

template <int CTRL>
__device__ __forceinline__ float dppadd(float x) {
  int y = __builtin_amdgcn_update_dpp(0, __float_as_int(x), CTRL, 0xF, 0xF, false);
  return x + __int_as_float(y);
}
// full 64-lane sum, valid in lane 63
__device__ __forceinline__ float wave_reduce63(float x) {
  x = dppadd<0x111>(x);  // row_shr:1
  x = dppadd<0x112>(x);  // row_shr:2
  x = dppadd<0x114>(x);  // row_shr:4
  x = dppadd<0x118>(x);  // row_shr:8  -> lane 15 of each row has row sum
  x = dppadd<0x142>(x);  // row_bcast:15
  x = dppadd<0x143>(x);  // row_bcast:31 -> lane 63 has total
  return x;
}

__device__ __forceinline__ float sigm(float x) {
  return 1.0f / (1.0f + __expf(-x));
}
__device__ __forceinline__ float tanh_(float x) {
  float t = __expf(-2.0f * fabsf(x));       // in (0,1] — overflow-safe
  float r = (1.0f - t) / (1.0f + t);
  return copysignf(r, x);
}

// ---------------- init kernel: zero tags, write initial h states ----------------
__global__ void lstm_init(const float* __restrict__ h0in, unsigned char* __restrict__ wsb) {
  const int i = blockIdx.x * blockDim.x + threadIdx.x;
  f16* h0b = (f16*)(wsb + H0_OFF);
  f16* h1b = (f16*)(wsb + H1_OFF);
  if (i < H) {
    h0b[i] = (f16)h0in[i];            // layer-0 initial hidden
  } else if (i < 2 * H) {
    h1b[i - H] = (f16)h0in[i];        // layer-1 initial hidden (h0in[1,0,:])
  } else if (i < 2 * H + NB) {
    ((int*)(wsb + TAG_OFF))[i - 2 * H] = 0;
  }
}

// ---------------- persistent LSTM kernel ----------------
// Round r (r = 0..SEQ):
//   needs h0buf[r] and h1buf[r-1] (published in round r-1; r=0 from init kernel)
//   L0 (if r < SEQ):  h0_{r+1} = cell(h0_r, x[r])        -> h0buf[r+1]
//   L1 (if r >= 1):   h1_r     = cell(h1_{r-1}, h0_r)    -> h1buf[r]
__global__ __launch_bounds__(NT, 2) void lstm_pers(
    const float* __restrict__ xin,   // [SEQ,2]
    const float* __restrict__ c0in,  // [2,1,H]
    const float* __restrict__ Wih0,  // [4H,2]
    const float* __restrict__ Whh0,  // [4H,H]
    const float* __restrict__ bih0,
    const float* __restrict__ bhh0,
    const float* __restrict__ Wih1,  // [4H,H]
    const float* __restrict__ Whh1,  // [4H,H]
    const float* __restrict__ bih1,
    const float* __restrict__ bhh1,
    unsigned char* __restrict__ wsb)
{
  const int b    = blockIdx.x;
  const int tid  = threadIdx.x;
  const int wave = tid >> 6;
  const int lane = tid & 63;

  int* tags = (int*)(wsb + TAG_OFF);
  f16* h0b  = (f16*)(wsb + H0_OFF);
  f16* h1b  = (f16*)(wsb + H1_OFF);

  // LDS: swizzled f16 h-vectors + z slots + combine state
  __shared__ __align__(16) unsigned char smem[4096 * 2 + 128 * 2 + 64 + 768];
  unsigned char* hs0 = smem;
  unsigned char* hs1 = smem + 4096;
  float* z0buf = (float*)(smem + 8192);         // 32 floats: layer-0 gate pre-acts
  float* z1buf = (float*)(smem + 8192 + 128);   // 32 floats: layer-1
  float* cbuf  = (float*)(smem + 8192 + 256);   // 16 floats: c state per combine thread
  float* xwb   = (float*)(smem + 8192 + 320);   // 16 threads x 12 floats (xw0[4],xw1[4],bsum[4])

  // ---- combine-thread state into LDS (threads 0..15) ----
  if (tid < 16) {
    const int layer = tid >> 3;
    const int jn    = tid & 7;
    float* xw = xwb + tid * 12;
    #pragma unroll
    for (int q = 0; q < 4; ++q) {
      const int R = q * H + b * JPB + jn;
      if (layer == 0) {
        xw[q]     = Wih0[(size_t)R * 2 + 0];
        xw[4 + q] = Wih0[(size_t)R * 2 + 1];
        xw[8 + q] = bih0[R] + bhh0[R];
      } else {
        xw[q]     = 0.0f;
        xw[4 + q] = 0.0f;
        xw[8 + q] = bih1[R] + bhh1[R];
      }
    }
    cbuf[tid] = c0in[layer * H + b * JPB + jn];
  }

  // ---- load weights into registers as packed f16 pairs ----
  // wave w owns unit (b*8 + w); rows m*H + b*8 + w for gates m=0..3 (i,f,g,o)
  // lane covers k = lane*32 .. lane*32+31  (16 f16 pairs per row per matrix)
  u32 wgt[4][3][16];
  {
    #pragma unroll
    for (int m = 0; m < 4; ++m) {
      const int R = m * H + b * JPB + wave;
      const float* srcs[3] = { Whh0 + (size_t)R * H, Wih1 + (size_t)R * H, Whh1 + (size_t)R * H };
      #pragma unroll
      for (int mat = 0; mat < 3; ++mat) {
        const float4* s4 = (const float4*)(srcs[mat] + lane * 32);
        #pragma unroll
        for (int i = 0; i < 8; ++i) {
          float4 f = s4[i];
          wgt[m][mat][2 * i]     = pk2(f.x, f.y);
          wgt[m][mat][2 * i + 1] = pk2(f.z, f.w);
        }
        __builtin_amdgcn_sched_barrier(0);  // cap transient register pressure
      }
    }
  }
  __syncthreads();

  int bailed = 0;  // hang-safety (wave 0 only)

  for (int r = 0; r < ROUNDS; ++r) {
    // ---- (1) wait for all blocks to finish round r-1 ----
    if (wave == 0 && r > 0) {
      if (!bailed) {
        int it = 0;
        while (1) {
          const int t0 = __hip_atomic_load(tags + lane,       __ATOMIC_RELAXED, __HIP_MEMORY_SCOPE_AGENT);
          const int t1 = __hip_atomic_load(tags + lane + 64,  __ATOMIC_RELAXED, __HIP_MEMORY_SCOPE_AGENT);
          const int t2 = __hip_atomic_load(tags + lane + 128, __ATOMIC_RELAXED, __HIP_MEMORY_SCOPE_AGENT);
          const int t3 = __hip_atomic_load(tags + lane + 192, __ATOMIC_RELAXED, __HIP_MEMORY_SCOPE_AGENT);
          const int ok = (t0 >= r) & (t1 >= r) & (t2 >= r) & (t3 >= r);
          if (__all(ok)) break;
          if (++it > (1 << 20)) { bailed = 1; break; }  // bail instead of hanging
          __builtin_amdgcn_s_sleep(1);
        }
      }
    }
    __syncthreads();

    // ---- (2) stage h0_r and h1_{r-1} into swizzled LDS (agent-scope loads from LLC) ----
    {
      const int rp = (r > 0) ? (r - 1) : 0;
      const u64* s0 = (const u64*)(h0b + (size_t)r  * H);
      const u64* s1 = (const u64*)(h1b + (size_t)rp * H);
      const u64 v0 = __hip_atomic_load(s0 + tid, __ATOMIC_RELAXED, __HIP_MEMORY_SCOPE_AGENT);
      const u64 v1 = __hip_atomic_load(s1 + tid, __ATOMIC_RELAXED, __HIP_MEMORY_SCOPE_AGENT);
      // quad q=tid holds f16 k = 4*tid..4*tid+3 ; swizzle: lane row 64B, chunk^(row&3)
      const int l = tid >> 3, c = (tid >> 1) & 3, o = (tid & 1) << 3;
      const int ba = (l << 6) + ((c ^ (l & 3)) << 4) + o;
      *(u64*)(hs0 + ba) = v0;
      *(u64*)(hs1 + ba) = v1;
    }
    __syncthreads();

    // ---- (3) dot products: 12 rows-worth per wave via v_dot2_f32_f16 ----
    float a0[4], aA[4], aB[4];
    #pragma unroll
    for (int m = 0; m < 4; ++m) { a0[m] = 0.f; aA[m] = 0.f; aB[m] = 0.f; }

    #pragma unroll
    for (int c = 0; c < 4; ++c) {
      const int ba = (lane << 6) + ((c ^ (lane & 3)) << 4);
      const uint4 u0 = *(const uint4*)(hs0 + ba);   // 8 f16 of h0_r   (pairs 4c..4c+3)
      const uint4 u1 = *(const uint4*)(hs1 + ba);   // 8 f16 of h1_{r-1}
      #pragma unroll
      for (int m = 0; m < 4; ++m) {
        a0[m] = dot2(wgt[m][0][4 * c + 0], u0.x, a0[m]);
        a0[m] = dot2(wgt[m][0][4 * c + 1], u0.y, a0[m]);
        a0[m] = dot2(wgt[m][0][4 * c + 2], u0.z, a0[m]);
        a0[m] = dot2(wgt[m][0][4 * c + 3], u0.w, a0[m]);
        aA[m] = dot2(wgt[m][1][4 * c + 0], u0.x, aA[m]);
        aA[m] = dot2(wgt[m][1][4 * c + 1], u0.y, aA[m]);
        aA[m] = dot2(wgt[m][1][4 * c + 2], u0.z, aA[m]);
        aA[m] = dot2(wgt[m][1][4 * c + 3], u0.w, aA[m]);
        aB[m] = dot2(wgt[m][2][4 * c + 0], u1.x, aB[m]);
        aB[m] = dot2(wgt[m][2][4 * c + 1], u1.y, aB[m]);
        aB[m] = dot2(wgt[m][2][4 * c + 2], u1.z, aB[m]);
        aB[m] = dot2(wgt[m][2][4 * c + 3], u1.w, aB[m]);
      }
    }

    // ---- (4) DPP reductions, write z slots ----
    #pragma unroll
    for (int m = 0; m < 4; ++m) {
      const float s0 = wave_reduce63(a0[m]);
      const float s1 = wave_reduce63(aA[m] + aB[m]);
      if (lane == 63) {
        z0buf[4 * wave + m] = s0;
        z1buf[4 * wave + m] = s1;
      }
    }
    __syncthreads();

    // ---- (5) combine: gates + state update + publish (wave 0, lanes 0..15) ----
    if (tid < 16) {
      const int layer = tid >> 3;
      const int jn    = tid & 7;
      const bool act  = (layer == 0) ? (r < SEQ) : (r >= 1);
      float hval = 0.0f;
      if (act) {
        const float* xw = xwb + tid * 12;
        float z[4];
        #pragma unroll
        for (int q = 0; q < 4; ++q)
          z[q] = ((layer == 0) ? z0buf[jn * 4 + q] : z1buf[jn * 4 + q]) + xw[8 + q];
        if (layer == 0) {
          const float x0v = xin[2 * r], x1v = xin[2 * r + 1];
          #pragma unroll
          for (int q = 0; q < 4; ++q) z[q] += xw[q] * x0v + xw[4 + q] * x1v;
        }
        float c = cbuf[tid];
        const float ig = sigm(z[0]);
        const float fg = sigm(z[1]);
        const float gg = tanh_(z[2]);
        const float og = sigm(z[3]);
        c = fg * c + ig * gg;
        cbuf[tid] = c;
        hval = og * tanh_(c);
      }
      // pack f16 pairs across even/odd lanes and store (agent scope, write-through)
      const f16 h16 = (f16)hval;
      const u32 hbits = (u32)__builtin_bit_cast(unsigned short, h16);
      const u32 nbits = __shfl_down(hbits, 1);
      if (act && !(tid & 1)) {
        const u32 pairv = hbits | (nbits << 16);
        u32* dst = (layer == 0)
            ? (u32*)(h0b + (size_t)(r + 1) * H) + (b * 4 + (jn >> 1))
            : (u32*)(h1b + (size_t)r * H)       + (b * 4 + (jn >> 1));
        __hip_atomic_store(dst, pairv, __ATOMIC_RELAXED, __HIP_MEMORY_SCOPE_AGENT);
      }
    }
    // ---- (6) publish tag (release orders the h stores before it) ----
    if (tid == 0) {
      __hip_atomic_store(tags + b, r + 1, __ATOMIC_RELEASE, __HIP_MEMORY_SCOPE_AGENT);
    }
  }
}

// ---------------- final linear: out = W_lin @ h1_SEQ + b_lin ----------------
__global__ void lstm_fin(const unsigned char* __restrict__ wsb,
                         const float* __restrict__ Wlin,   // [2,H]
                         const float* __restrict__ blin,   // [2]
                         float* __restrict__ out)
{
  __shared__ float red[2][4];
  const f16* h1 = (const f16*)(wsb + H1_OFF) + (size_t)SEQ * H;
  const int tid = threadIdx.x;  // 256 threads
  float p0 = 0.f, p1 = 0.f;
  for (int k = tid; k < H; k += 256) {
    const float h = (float)h1[k];
    p0 += h * Wlin[k];
    p1 += h * Wlin[H + k];
  }
  p0 = wave_reduce63(p0);
  p1 = wave_reduce63(p1);
  const int wv = tid >> 6, ln = tid & 63;
  if (ln == 63) { red[0][wv] = p0; red[1][wv] = p1; }
  __syncthreads();
  if (tid == 0) {
    out[0] = blin[0] + red[0][0] + red[0][1] + red[0][2] + red[0][3];
    out[1] = blin[1] + red[1][0] + red[1][1] + red[1][2] + red[1][3];
  }
}

extern "C" void kernel_launch(void* const* d_in, const int* in_sizes, int n_in,
                              void* d_out, int out_size, void* d_ws, size_t ws_size,
                              hipStream_t stream) {
  const float* xin  = (const float*)d_in[0];
  const float* h0in = (const float*)d_in[1];
  const float* c0in = (const float*)d_in[2];
  const float* Wih0 = (const float*)d_in[3];
  const float* Whh0 = (const float*)d_in[4];
  const float* bih0 = (const float*)d_in[5];
  const float* bhh0 = (const float*)d_in[6];
  const float* Wih1 = (const float*)d_in[7];
  const float* Whh1 = (const float*)d_in[8];
  const float* bih1 = (const float*)d_in[9];
  const float* bhh1 = (const float*)d_in[10];
  const float* Wlin = (const float*)d_in[11];
  const float* blin = (const float*)d_in[12];
  unsigned char* wsb = (unsigned char*)d_ws;

  if (ws_size < WS_NEED) return;  // fail visibly (output stays poisoned)

  lstm_init<<<dim3((2 * H + NB + 255) / 256), dim3(256), 0, stream>>>(h0in, wsb);
  lstm_pers<<<dim3(NB), dim3(NT), 0, stream>>>(xin, c0in, Wih0, Whh0, bih0, bhh0,
                                               Wih1, Whh1, bih1, bhh1, wsb);
  lstm_fin<<<dim3(1), dim3(256), 0, stream>>>(wsb, Wlin, blin, (float*)d_out);
}

// Round 3
// 3639.460 us; speedup vs baseline: 2.2563x; 2.2563x over previous
//
#include <hip/hip_runtime.h>
#include <stdint.h>

// ---------------- problem constants ----------------
#define H      2048
#define SEQ    1024
#define NB     256      // persistent blocks (1 per CU)
#define NT     512      // threads per block (8 waves)
#define JPB    8        // hidden units per block per layer (H / NB)
#define ROUNDS (SEQ + 1)
#define SENT32 0x7C007C00u   // two f16 +inf — unreachable as produced h (|h|<1)

typedef _Float16 f16;
typedef _Float16 f16x2 __attribute__((ext_vector_type(2)));
typedef unsigned int u32;
typedef unsigned long long u64;

// ---------------- workspace layout (bytes) ----------------
// h0buf: f16[SEQ+2][H] @ H0_OFF   (h0buf[t] = layer-0 hidden after t steps)
// h1buf: f16[SEQ+2][H] @ H1_OFF
static const size_t H0_OFF  = 4096;
static const size_t HBYTES  = (size_t)(SEQ + 2) * H * 2;   // 4,202,496
static const size_t H1_OFF  = H0_OFF + HBYTES;
static const size_t WS_NEED = H1_OFF + HBYTES;             // ~8.4 MB

// ---------------- helpers ----------------
__device__ __forceinline__ u32 pk2(float a, float b) {
  f16x2 h;
  h.x = (f16)a;  // RNE
  h.y = (f16)b;
  return __builtin_bit_cast(u32, h);
}

__device__ __forceinline__ float dot2(u32 a, u32 b, float c) {
#if __has_builtin(__builtin_amdgcn_fdot2)
  return __builtin_amdgcn_fdot2(__builtin_bit_cast(f16x2, a),
                                __builtin_bit_cast(f16x2, b), c, false);
#else
  f16x2 av = __builtin_bit_cast(f16x2, a);
  f16x2 bv = __builtin_bit_cast(f16x2, b);
  return c + (float)av.x * (float)bv.x + (float)av.y * (float)bv.y;
#endif
}

template <int CTRL>
__device__ __forceinline__ float dppadd(float x) {
  int y = __builtin_amdgcn_update_dpp(0, __float_as_int(x), CTRL, 0xF, 0xF, false);
  return x + __int_as_float(y);
}
// full 64-lane sum, valid in lane 63
__device__ __forceinline__ float wave_reduce63(float x) {
  x = dppadd<0x111>(x);  // row_shr:1
  x = dppadd<0x112>(x);  // row_shr:2
  x = dppadd<0x114>(x);  // row_shr:4
  x = dppadd<0x118>(x);  // row_shr:8  -> lane 15 of each row has row sum
  x = dppadd<0x142>(x);  // row_bcast:15
  x = dppadd<0x143>(x);  // row_bcast:31 -> lane 63 has total
  return x;
}

__device__ __forceinline__ float sigm(float x) {
  return 1.0f / (1.0f + __expf(-x));
}
__device__ __forceinline__ float tanh_(float x) {
  float t = __expf(-2.0f * fabsf(x));       // in (0,1] — overflow-safe
  float r = (1.0f - t) / (1.0f + t);
  return copysignf(r, x);
}

// ---------------- init kernel: sentinel-fill h buffers, write initial states ----------------
// Must run every call (harness only poisons once; replays need fresh sentinels).
#define PER_BUF_U32 ((SEQ + 1) * (H / 2))   // u32 words per buffer, rows 0..SEQ
__global__ void lstm_init(const float* __restrict__ h0in, unsigned char* __restrict__ wsb) {
  const int i = blockIdx.x * blockDim.x + threadIdx.x;
  u32* b0 = (u32*)(wsb + H0_OFF);
  u32* b1 = (u32*)(wsb + H1_OFF);
  if (i < H / 2) {
    // row 0 = initial hidden states (h0in layout: [2,1,H])
    b0[i] = pk2(h0in[2 * i], h0in[2 * i + 1]);
    b1[i] = pk2(h0in[H + 2 * i], h0in[H + 2 * i + 1]);
  } else if (i < PER_BUF_U32) {
    b0[i] = SENT32;
    b1[i] = SENT32;
  }
}

// ---------------- persistent LSTM kernel (data-flow sync, no barrier) ----------------
// Round r (r = 0..SEQ):
//   needs h0buf[r] and h1buf[r-1] (polled directly — sentinel means not ready)
//   L0 (if r < SEQ):  h0_{r+1} = cell(h0_r, x[r])        -> h0buf[r+1]
//   L1 (if r >= 1):   h1_r     = cell(h1_{r-1}, h0_r)    -> h1buf[r]
__global__ __launch_bounds__(NT, 2) void lstm_pers(
    const float* __restrict__ xin,   // [SEQ,2]
    const float* __restrict__ c0in,  // [2,1,H]
    const float* __restrict__ Wih0,  // [4H,2]
    const float* __restrict__ Whh0,  // [4H,H]
    const float* __restrict__ bih0,
    const float* __restrict__ bhh0,
    const float* __restrict__ Wih1,  // [4H,H]
    const float* __restrict__ Whh1,  // [4H,H]
    const float* __restrict__ bih1,
    const float* __restrict__ bhh1,
    unsigned char* __restrict__ wsb)
{
  const int b    = blockIdx.x;
  const int tid  = threadIdx.x;
  const int lane = tid & 63;
  const int wave = tid >> 6;

  f16* h0b = (f16*)(wsb + H0_OFF);
  f16* h1b = (f16*)(wsb + H1_OFF);

  // LDS: padded-row h stages (64 rows x 80B -> bank starts cycle all 32 banks)
  __shared__ __align__(16) unsigned char smem[5120 * 2 + 128 * 2 + 64 + 768];
  unsigned char* hs0 = smem;
  unsigned char* hs1 = smem + 5120;
  float* z0buf = (float*)(smem + 10240);        // 32 floats: layer-0 gate pre-acts
  float* z1buf = (float*)(smem + 10240 + 128);  // 32 floats: layer-1
  float* cbuf  = (float*)(smem + 10240 + 256);  // 16 floats: c state per combine thread
  float* xwb   = (float*)(smem + 10240 + 320);  // 16 threads x 12 floats

  // ---- combine-thread state into LDS (threads 0..15) ----
  if (tid < 16) {
    const int layer = tid >> 3;
    const int jn    = tid & 7;
    float* xw = xwb + tid * 12;
    #pragma unroll
    for (int q = 0; q < 4; ++q) {
      const int R = q * H + b * JPB + jn;
      if (layer == 0) {
        xw[q]     = Wih0[(size_t)R * 2 + 0];
        xw[4 + q] = Wih0[(size_t)R * 2 + 1];
        xw[8 + q] = bih0[R] + bhh0[R];
      } else {
        xw[q]     = 0.0f;
        xw[4 + q] = 0.0f;
        xw[8 + q] = bih1[R] + bhh1[R];
      }
    }
    cbuf[tid] = c0in[layer * H + b * JPB + jn];
  }

  // ---- load weights into registers as packed f16 pairs ----
  // wave w owns unit (b*8 + w); rows m*H + b*8 + w for gates m=0..3 (i,f,g,o)
  // lane covers k = lane*32 .. lane*32+31  (16 f16 pairs per row per matrix)
  u32 wgt[4][3][16];
  {
    #pragma unroll
    for (int m = 0; m < 4; ++m) {
      const int R = m * H + b * JPB + wave;
      const float* srcs[3] = { Whh0 + (size_t)R * H, Wih1 + (size_t)R * H, Whh1 + (size_t)R * H };
      #pragma unroll
      for (int mat = 0; mat < 3; ++mat) {
        const float4* s4 = (const float4*)(srcs[mat] + lane * 32);
        #pragma unroll
        for (int i = 0; i < 8; ++i) {
          float4 f = s4[i];
          wgt[m][mat][2 * i]     = pk2(f.x, f.y);
          wgt[m][mat][2 * i + 1] = pk2(f.z, f.w);
        }
        __builtin_amdgcn_sched_barrier(0);  // cap transient register pressure
      }
    }
  }
  __syncthreads();

  const int row = tid >> 3, q = tid & 7;       // LDS write slot (80B row pitch)
  const int wba = row * 80 + q * 8;

  for (int r = 0; r < ROUNDS; ++r) {
    // ---- (1) poll own h slices directly (one LLC hop; sentinel = not ready) ----
    {
      const int rp = (r > 0) ? (r - 1) : 0;
      const u64* s0 = (const u64*)h0b + (size_t)r  * (H / 4) + tid;
      const u64* s1 = (const u64*)h1b + (size_t)rp * (H / 4) + tid;
      u64 v0 = 0, v1 = 0;
      bool ok0 = false, ok1 = false;
      int it = 0;
      while (true) {
        if (!ok0) {
          v0 = __hip_atomic_load(s0, __ATOMIC_RELAXED, __HIP_MEMORY_SCOPE_AGENT);
          ok0 = ((u32)v0 != SENT32) && ((u32)(v0 >> 32) != SENT32);
        }
        if (!ok1) {
          v1 = __hip_atomic_load(s1, __ATOMIC_RELAXED, __HIP_MEMORY_SCOPE_AGENT);
          ok1 = ((u32)v1 != SENT32) && ((u32)(v1 >> 32) != SENT32);
        }
        if (ok0 && ok1) break;
        if (++it > (1 << 20)) break;           // hang-safety: bail, wrong but terminates
        __builtin_amdgcn_s_sleep(1);
      }
      *(u64*)(hs0 + wba) = v0;
      *(u64*)(hs1 + wba) = v1;
    }
    __syncthreads();

    // ---- (2) dot products: 12 rows-worth per wave via v_dot2_f32_f16 ----
    float a0[4], aA[4], aB[4];
    #pragma unroll
    for (int m = 0; m < 4; ++m) { a0[m] = 0.f; aA[m] = 0.f; aB[m] = 0.f; }

    #pragma unroll
    for (int c = 0; c < 4; ++c) {
      const int ba = lane * 80 + c * 16;
      const uint4 u0 = *(const uint4*)(hs0 + ba);   // 8 f16 of h0_r
      const uint4 u1 = *(const uint4*)(hs1 + ba);   // 8 f16 of h1_{r-1}
      #pragma unroll
      for (int m = 0; m < 4; ++m) {
        a0[m] = dot2(wgt[m][0][4 * c + 0], u0.x, a0[m]);
        a0[m] = dot2(wgt[m][0][4 * c + 1], u0.y, a0[m]);
        a0[m] = dot2(wgt[m][0][4 * c + 2], u0.z, a0[m]);
        a0[m] = dot2(wgt[m][0][4 * c + 3], u0.w, a0[m]);
        aA[m] = dot2(wgt[m][1][4 * c + 0], u0.x, aA[m]);
        aA[m] = dot2(wgt[m][1][4 * c + 1], u0.y, aA[m]);
        aA[m] = dot2(wgt[m][1][4 * c + 2], u0.z, aA[m]);
        aA[m] = dot2(wgt[m][1][4 * c + 3], u0.w, aA[m]);
        aB[m] = dot2(wgt[m][2][4 * c + 0], u1.x, aB[m]);
        aB[m] = dot2(wgt[m][2][4 * c + 1], u1.y, aB[m]);
        aB[m] = dot2(wgt[m][2][4 * c + 2], u1.z, aB[m]);
        aB[m] = dot2(wgt[m][2][4 * c + 3], u1.w, aB[m]);
      }
    }

    // ---- (3) DPP reductions, write z slots ----
    #pragma unroll
    for (int m = 0; m < 4; ++m) {
      const float s0 = wave_reduce63(a0[m]);
      const float s1 = wave_reduce63(aA[m] + aB[m]);
      if (lane == 63) {
        z0buf[4 * wave + m] = s0;
        z1buf[4 * wave + m] = s1;
      }
    }
    __syncthreads();

    // ---- (4) combine: gates + state update + publish (wave 0, lanes 0..15) ----
    if (tid < 16) {
      const int layer = tid >> 3;
      const int jn    = tid & 7;
      const bool act  = (layer == 0) ? (r < SEQ) : (r >= 1);
      float hval = 0.0f;
      if (act) {
        const float* xw = xwb + tid * 12;
        float z[4];
        #pragma unroll
        for (int qq = 0; qq < 4; ++qq)
          z[qq] = ((layer == 0) ? z0buf[jn * 4 + qq] : z1buf[jn * 4 + qq]) + xw[8 + qq];
        if (layer == 0) {
          const float x0v = xin[2 * r], x1v = xin[2 * r + 1];
          #pragma unroll
          for (int qq = 0; qq < 4; ++qq) z[qq] += xw[qq] * x0v + xw[4 + qq] * x1v;
        }
        float c = cbuf[tid];
        const float ig = sigm(z[0]);
        const float fg = sigm(z[1]);
        const float gg = tanh_(z[2]);
        const float og = sigm(z[3]);
        c = fg * c + ig * gg;
        cbuf[tid] = c;
        hval = og * tanh_(c);
      }
      // pack f16 pairs across even/odd lanes and store (agent scope)
      const f16 h16 = (f16)hval;
      const u32 hbits = (u32)__builtin_bit_cast(unsigned short, h16);
      const u32 nbits = __shfl_down(hbits, 1);
      if (act && !(tid & 1)) {
        const u32 pairv = hbits | (nbits << 16);
        u32* dst = (layer == 0)
            ? (u32*)(h0b + (size_t)(r + 1) * H) + (b * 4 + (jn >> 1))
            : (u32*)(h1b + (size_t)r * H)       + (b * 4 + (jn >> 1));
        __hip_atomic_store(dst, pairv, __ATOMIC_RELAXED, __HIP_MEMORY_SCOPE_AGENT);
      }
    }
    // no tag, no barrier: consumers poll the data itself
  }
}

// ---------------- final linear: out = W_lin @ h1_SEQ + b_lin ----------------
__global__ void lstm_fin(const unsigned char* __restrict__ wsb,
                         const float* __restrict__ Wlin,   // [2,H]
                         const float* __restrict__ blin,   // [2]
                         float* __restrict__ out)
{
  __shared__ float red[2][4];
  const f16* h1 = (const f16*)(wsb + H1_OFF) + (size_t)SEQ * H;
  const int tid = threadIdx.x;  // 256 threads
  float p0 = 0.f, p1 = 0.f;
  for (int k = tid; k < H; k += 256) {
    const float h = (float)h1[k];
    p0 += h * Wlin[k];
    p1 += h * Wlin[H + k];
  }
  p0 = wave_reduce63(p0);
  p1 = wave_reduce63(p1);
  const int wv = tid >> 6, ln = tid & 63;
  if (ln == 63) { red[0][wv] = p0; red[1][wv] = p1; }
  __syncthreads();
  if (tid == 0) {
    out[0] = blin[0] + red[0][0] + red[0][1] + red[0][2] + red[0][3];
    out[1] = blin[1] + red[1][0] + red[1][1] + red[1][2] + red[1][3];
  }
}

extern "C" void kernel_launch(void* const* d_in, const int* in_sizes, int n_in,
                              void* d_out, int out_size, void* d_ws, size_t ws_size,
                              hipStream_t stream) {
  const float* xin  = (const float*)d_in[0];
  const float* h0in = (const float*)d_in[1];
  const float* c0in = (const float*)d_in[2];
  const float* Wih0 = (const float*)d_in[3];
  const float* Whh0 = (const float*)d_in[4];
  const float* bih0 = (const float*)d_in[5];
  const float* bhh0 = (const float*)d_in[6];
  const float* Wih1 = (const float*)d_in[7];
  const float* Whh1 = (const float*)d_in[8];
  const float* bih1 = (const float*)d_in[9];
  const float* bhh1 = (const float*)d_in[10];
  const float* Wlin = (const float*)d_in[11];
  const float* blin = (const float*)d_in[12];
  unsigned char* wsb = (unsigned char*)d_ws;

  if (ws_size < WS_NEED) return;  // fail visibly (output stays poisoned)

  lstm_init<<<dim3((PER_BUF_U32 + 255) / 256), dim3(256), 0, stream>>>(h0in, wsb);
  lstm_pers<<<dim3(NB), dim3(NT), 0, stream>>>(xin, c0in, Wih0, Whh0, bih0, bhh0,
                                               Wih1, Whh1, bih1, bhh1, wsb);
  lstm_fin<<<dim3(1), dim3(256), 0, stream>>>(wsb, Wlin, blin, (float*)d_out);
}